// Round 1
// baseline (913.676 us; speedup 1.0000x reference)
//
#include <hip/hip_runtime.h>

constexpr int N_NODES = 100000;
constexpr int N_EDGES = 1600000;
constexpr int D = 64;

// ---- bucketed semisort parameters ----
constexpr int BUCK_BITS = 6;                                   // 64 nodes / bucket
constexpr int BUCK_SZ   = 1 << BUCK_BITS;
constexpr int NBUCK     = (N_NODES + BUCK_SZ - 1) / BUCK_SZ;   // 1563

// ---------- fast path ----------

// Y[i] = vertices[i] @ W^T   (bias deferred to gather). 4 waves/block, 1 node/wave.
__global__ __launch_bounds__(256) void linear_kernel(
    const float* __restrict__ vertices,
    const float* __restrict__ weight,   // [64][64] row-major
    float* __restrict__ Y)
{
    __shared__ float rowbuf[4][64];
    const int wid  = threadIdx.x >> 6;
    const int lane = threadIdx.x & 63;

    float w[64];
    #pragma unroll
    for (int f = 0; f < 64; ++f) w[f] = weight[lane * 64 + f];

    const int nodesPerIter = gridDim.x * 4;
    for (int base = blockIdx.x * 4; base < N_NODES; base += nodesPerIter) {
        const int node = base + wid;
        float a = 0.0f;
        if (node < N_NODES) a = vertices[(size_t)node * D + lane];
        rowbuf[wid][lane] = a;
        __syncthreads();
        float acc = 0.0f;
        #pragma unroll
        for (int f = 0; f < 64; ++f)
            acc += rowbuf[wid][f] * w[f];       // same-address broadcast
        if (node < N_NODES) Y[(size_t)node * D + lane] = acc;
        __syncthreads();
    }
}

// LDS-staged histogram over dst buckets.
__global__ __launch_bounds__(256) void bucket_hist(const int* __restrict__ edges,
                                                   int* __restrict__ bcnt)
{
    __shared__ int h[NBUCK];
    for (int i = threadIdx.x; i < NBUCK; i += 256) h[i] = 0;
    __syncthreads();
    const int stride = gridDim.x * 256;
    for (int e = blockIdx.x * 256 + threadIdx.x; e < N_EDGES; e += stride)
        atomicAdd(&h[edges[e] >> BUCK_BITS], 1);
    __syncthreads();
    for (int i = threadIdx.x; i < NBUCK; i += 256) {
        int v = h[i];
        if (v) atomicAdd(&bcnt[i], v);
    }
}

// Exclusive scan of NBUCK (<=2048) counters; single block of 1024 threads.
__global__ void bucket_scan(const int* __restrict__ bcnt,
                            int* __restrict__ boff,
                            int* __restrict__ bcur)
{
    __shared__ int s[1024];
    const int t = threadIdx.x;
    int a = (2 * t     < NBUCK) ? bcnt[2 * t]     : 0;
    int b = (2 * t + 1 < NBUCK) ? bcnt[2 * t + 1] : 0;
    int pair = a + b;
    s[t] = pair;
    __syncthreads();
    for (int o = 1; o < 1024; o <<= 1) {
        int u = (t >= o) ? s[t - o] : 0;
        __syncthreads();
        s[t] += u;
        __syncthreads();
    }
    int excl = s[t] - pair;                 // exclusive over pairs
    if (2 * t < NBUCK)     { boff[2 * t]     = excl;     bcur[2 * t]     = excl; }
    if (2 * t + 1 < NBUCK) { boff[2 * t + 1] = excl + a; bcur[2 * t + 1] = excl + a; }
}

// Semisort: append (src<<6 | dst&63) to the dst's bucket run. Writes are
// frontier-sequential per bucket -> full-line writebacks (~6.4 MB total).
__global__ __launch_bounds__(256) void partition_kernel(const int* __restrict__ edges,
                                                        int* __restrict__ bcur,
                                                        int* __restrict__ packed)
{
    int e = blockIdx.x * 256 + threadIdx.x;
    if (e >= N_EDGES) return;
    int dst = edges[e];
    int src = edges[N_EDGES + e];
    int b = dst >> BUCK_BITS;
    int pos = atomicAdd(&bcur[b], 1);
    packed[pos] = (src << BUCK_BITS) | (dst & (BUCK_SZ - 1));
}

// One block per bucket: accumulate gathered Y rows into LDS, count deg in LDS,
// fuse self-loop + rsqrt scale + bias + store.
__global__ __launch_bounds__(256) void bucket_gather(
    const float* __restrict__ Y,
    const int* __restrict__ boff,
    const int* __restrict__ bcnt,
    const int* __restrict__ packed,
    const float* __restrict__ bias,
    float* __restrict__ out)
{
    __shared__ float acc[BUCK_SZ * 64];
    __shared__ int degc[BUCK_SZ];

    const int wid  = threadIdx.x >> 6;
    const int lane = threadIdx.x & 63;

    for (int i = threadIdx.x; i < BUCK_SZ * 64; i += 256) acc[i] = 0.0f;
    if (threadIdx.x < BUCK_SZ) degc[threadIdx.x] = 0;
    __syncthreads();

    const int b     = blockIdx.x;
    const int start = boff[b];
    const int cnt   = bcnt[b];
    const int base  = b << BUCK_BITS;

    int i = wid;
    for (; i + 12 < cnt; i += 16) {
        int p0 = packed[start + i];
        int p1 = packed[start + i + 4];
        int p2 = packed[start + i + 8];
        int p3 = packed[start + i + 12];
        float a0 = Y[((p0 >> BUCK_BITS) << 6) + lane];
        float a1 = Y[((p1 >> BUCK_BITS) << 6) + lane];
        float a2 = Y[((p2 >> BUCK_BITS) << 6) + lane];
        float a3 = Y[((p3 >> BUCK_BITS) << 6) + lane];
        atomicAdd(&acc[((p0 & (BUCK_SZ - 1)) << 6) + lane], a0);
        atomicAdd(&acc[((p1 & (BUCK_SZ - 1)) << 6) + lane], a1);
        atomicAdd(&acc[((p2 & (BUCK_SZ - 1)) << 6) + lane], a2);
        atomicAdd(&acc[((p3 & (BUCK_SZ - 1)) << 6) + lane], a3);
        if (lane == 0) {
            atomicAdd(&degc[p0 & (BUCK_SZ - 1)], 1);
            atomicAdd(&degc[p1 & (BUCK_SZ - 1)], 1);
            atomicAdd(&degc[p2 & (BUCK_SZ - 1)], 1);
            atomicAdd(&degc[p3 & (BUCK_SZ - 1)], 1);
        }
    }
    for (; i < cnt; i += 4) {
        int p = packed[start + i];
        float a = Y[((p >> BUCK_BITS) << 6) + lane];
        atomicAdd(&acc[((p & (BUCK_SZ - 1)) << 6) + lane], a);
        if (lane == 0) atomicAdd(&degc[p & (BUCK_SZ - 1)], 1);
    }
    __syncthreads();

    const float bl = bias[lane];
    for (int local = wid; local < BUCK_SZ; local += 4) {
        int node = base + local;
        if (node < N_NODES) {
            float v = acc[(local << 6) + lane] + Y[(size_t)node * 64 + lane];  // self loop
            out[(size_t)node * 64 + lane] = v * rsqrtf((float)degc[local] + 1.0f) + bl;
        }
    }
}

// ---------- fallback path (round-1, proven) ----------

__global__ __launch_bounds__(256) void fb_scatter(
    const float* __restrict__ vertices, const int* __restrict__ edges,
    float* __restrict__ agg, float* __restrict__ degF)
{
    long long tid = (long long)blockIdx.x * 256 + threadIdx.x;
    int lane = threadIdx.x & 63;
    long long e = tid >> 6;
    if (e >= N_EDGES) return;
    int dst = edges[e];
    int src = edges[N_EDGES + e];
    atomicAdd(&agg[(size_t)dst * D + lane], vertices[(size_t)src * D + lane]);
    if (lane == 0) atomicAdd(&degF[dst], 1.0f);
}

__global__ __launch_bounds__(256) void fb_finish(
    const float* __restrict__ vertices, const float* __restrict__ weight,
    const float* __restrict__ bias, const float* __restrict__ degF,
    float* __restrict__ out)
{
    __shared__ float rowbuf[4][64];
    const int wid  = threadIdx.x >> 6;
    const int lane = threadIdx.x & 63;
    float w[64];
    #pragma unroll
    for (int f = 0; f < 64; ++f) w[f] = weight[lane * 64 + f];
    const float b = bias[lane];
    const int nodesPerIter = gridDim.x * 4;
    for (int base = blockIdx.x * 4; base < N_NODES; base += nodesPerIter) {
        const int node = base + wid;
        float a = 0.0f;
        if (node < N_NODES) {
            const float scale = rsqrtf(degF[node] + 1.0f);
            a = (out[(size_t)node * D + lane] + vertices[(size_t)node * D + lane]) * scale;
        }
        rowbuf[wid][lane] = a;
        __syncthreads();
        float acc = b;
        #pragma unroll
        for (int f = 0; f < 64; ++f) acc += rowbuf[wid][f] * w[f];
        if (node < N_NODES) out[(size_t)node * D + lane] = acc;
        __syncthreads();
    }
}

extern "C" void kernel_launch(void* const* d_in, const int* in_sizes, int n_in,
                              void* d_out, int out_size, void* d_ws, size_t ws_size,
                              hipStream_t stream) {
    const float* vertices = (const float*)d_in[0];
    const int*   edges    = (const int*)d_in[1];
    const float* weight   = (const float*)d_in[2];
    const float* bias     = (const float*)d_in[3];
    float* out = (float*)d_out;

    // ws layout: Y[N*64] f32 | bcnt[NBUCK] | boff[NBUCK] | bcur[NBUCK] | packed[E]
    float* Y      = (float*)d_ws;
    int*   bcnt   = (int*)(Y + (size_t)N_NODES * D);
    int*   boff   = bcnt + NBUCK;
    int*   bcur   = boff + NBUCK;
    int*   packed = bcur + NBUCK;
    size_t needed = (size_t)((char*)(packed + N_EDGES) - (char*)d_ws);

    const int threads = 256;
    const int edgeBlocks = (N_EDGES + threads - 1) / threads;

    if (ws_size >= needed) {
        hipMemsetAsync(bcnt, 0, sizeof(int) * NBUCK, stream);
        linear_kernel<<<1024, threads, 0, stream>>>(vertices, weight, Y);
        bucket_hist<<<1024, threads, 0, stream>>>(edges, bcnt);
        bucket_scan<<<1, 1024, 0, stream>>>(bcnt, boff, bcur);
        partition_kernel<<<edgeBlocks, threads, 0, stream>>>(edges, bcur, packed);
        bucket_gather<<<NBUCK, threads, 0, stream>>>(Y, boff, bcnt, packed, bias, out);
    } else {
        float* degF = (float*)d_ws;
        hipMemsetAsync(out, 0, sizeof(float) * (size_t)N_NODES * D, stream);
        hipMemsetAsync(degF, 0, sizeof(float) * N_NODES, stream);
        const long long totalScatter = (long long)N_EDGES * 64;
        fb_scatter<<<(int)((totalScatter + threads - 1) / threads), threads, 0, stream>>>(
            vertices, edges, out, degF);
        fb_finish<<<1024, threads, 0, stream>>>(vertices, weight, bias, degF, out);
    }
}

// Round 2
// 152.115 us; speedup vs baseline: 6.0065x; 6.0065x over previous
//
#include <hip/hip_runtime.h>

constexpr int N_NODES = 100000;
constexpr int N_EDGES = 1600000;
constexpr int D = 64;

// ---- deterministic two-level split parameters ----
constexpr int SH     = 9;                                  // 512 nodes / bucket
constexpr int BSZ    = 1 << SH;                            // 512
constexpr int NB     = (N_NODES + BSZ - 1) / BSZ;          // 196 buckets
constexpr int SPLITB = 256;                                // split grid blocks
constexpr int TILE   = (N_EDGES + SPLITB - 1) / SPLITB;    // 6250 edges / block

// ---- mid-tier (round-0 proven) scan parameters ----
constexpr int SCAN_CHUNK = 1024;
constexpr int NCHUNK = (N_NODES + SCAN_CHUNK - 1) / SCAN_CHUNK;   // 98

// ---------------------------------------------------------------------------
// shared kernels (proven round-0)
// ---------------------------------------------------------------------------

// Y[i] = vertices[i] @ W^T   (bias deferred to gather). 4 waves/block, 1 node/wave.
__global__ __launch_bounds__(256) void linear_kernel(
    const float* __restrict__ vertices,
    const float* __restrict__ weight,   // [64][64] row-major
    float* __restrict__ Y)
{
    __shared__ float rowbuf[4][64];
    const int wid  = threadIdx.x >> 6;
    const int lane = threadIdx.x & 63;

    float w[64];
    #pragma unroll
    for (int f = 0; f < 64; ++f) w[f] = weight[lane * 64 + f];

    const int nodesPerIter = gridDim.x * 4;
    for (int base = blockIdx.x * 4; base < N_NODES; base += nodesPerIter) {
        const int node = base + wid;
        float a = 0.0f;
        if (node < N_NODES) a = vertices[(size_t)node * D + lane];
        rowbuf[wid][lane] = a;
        __syncthreads();
        float acc = 0.0f;
        #pragma unroll
        for (int f = 0; f < 64; ++f)
            acc += rowbuf[wid][f] * w[f];       // same-address broadcast
        if (node < N_NODES) Y[(size_t)node * D + lane] = acc;
        __syncthreads();
    }
}

// One wave per node: register-accumulate gathered Y rows; scale + bias; write out.
__global__ __launch_bounds__(256) void gather_kernel(
    const float* __restrict__ Y,
    const int* __restrict__ offsets,
    const int* __restrict__ deg,
    const int* __restrict__ sortedSrc,
    const float* __restrict__ bias,
    float* __restrict__ out)
{
    const int wid  = threadIdx.x >> 6;
    const int lane = threadIdx.x & 63;
    const int node = blockIdx.x * 4 + wid;
    if (node >= N_NODES) return;

    float acc = Y[(size_t)node * D + lane];      // self loop
    const int start = offsets[node];
    const int cnt   = deg[node];

    int e = 0;
    for (; e + 4 <= cnt; e += 4) {
        int s0 = sortedSrc[start + e + 0];
        int s1 = sortedSrc[start + e + 1];
        int s2 = sortedSrc[start + e + 2];
        int s3 = sortedSrc[start + e + 3];
        float a0 = Y[(size_t)s0 * D + lane];
        float a1 = Y[(size_t)s1 * D + lane];
        float a2 = Y[(size_t)s2 * D + lane];
        float a3 = Y[(size_t)s3 * D + lane];
        acc += a0; acc += a1; acc += a2; acc += a3;
    }
    for (; e < cnt; ++e)
        acc += Y[(size_t)sortedSrc[start + e] * D + lane];

    out[(size_t)node * D + lane] = acc * rsqrtf((float)cnt + 1.0f) + bias[lane];
}

// ---------------------------------------------------------------------------
// fast path: deterministic split (no global atomics)
// ---------------------------------------------------------------------------

// Pass 1: per-block LDS histogram over 196 buckets -> H[block][bucket].
__global__ __launch_bounds__(256) void s_hist(const int* __restrict__ edges,
                                              int* __restrict__ H)
{
    __shared__ int h[NB];
    for (int i = threadIdx.x; i < NB; i += 256) h[i] = 0;
    __syncthreads();
    const int lo = blockIdx.x * TILE;
    const int hi = min(lo + TILE, N_EDGES);
    for (int e = lo + threadIdx.x; e < hi; e += 256)
        atomicAdd(&h[edges[e] >> SH], 1);
    __syncthreads();
    for (int i = threadIdx.x; i < NB; i += 256)
        H[blockIdx.x * NB + i] = h[i];
}

// Scan A: one block per bucket; exclusive-scan its column of H (SPLITB rows),
// leave exclusive values in place, emit column total.
__global__ __launch_bounds__(256) void s_scanA(int* __restrict__ H,
                                               int* __restrict__ colsum)
{
    const int j = blockIdx.x;
    const int t = threadIdx.x;
    int v = H[t * NB + j];
    __shared__ int s[256];
    s[t] = v; __syncthreads();
    for (int o = 1; o < 256; o <<= 1) {
        int u = (t >= o) ? s[t - o] : 0;
        __syncthreads();
        s[t] += u;
        __syncthreads();
    }
    H[t * NB + j] = s[t] - v;            // exclusive within column
    if (t == 255) colsum[j] = s[t];
}

// Scan B: exclusive scan of the 196 column totals -> bucket base offsets.
__global__ void s_scanB(const int* __restrict__ colsum, int* __restrict__ bbase)
{
    __shared__ int s[256];
    const int t = threadIdx.x;
    int v = (t < NB) ? colsum[t] : 0;
    s[t] = v; __syncthreads();
    for (int o = 1; o < 256; o <<= 1) {
        int u = (t >= o) ? s[t - o] : 0;
        __syncthreads();
        s[t] += u;
        __syncthreads();
    }
    if (t < NB) bbase[t] = s[t] - v;
}

// Pass 2: re-read edges; rank via LDS cursor (pre-seeded with the deterministic
// global offset), write packed (src<<9 | dst&511). Each (block,bucket) run is
// contiguous and single-writer -> full-line writebacks.
__global__ __launch_bounds__(256) void s_scatter(const int* __restrict__ edges,
                                                 const int* __restrict__ H,
                                                 const int* __restrict__ bbase,
                                                 int* __restrict__ packed)
{
    __shared__ int cur[NB];
    for (int i = threadIdx.x; i < NB; i += 256)
        cur[i] = bbase[i] + H[blockIdx.x * NB + i];
    __syncthreads();
    const int lo = blockIdx.x * TILE;
    const int hi = min(lo + TILE, N_EDGES);
    for (int e = lo + threadIdx.x; e < hi; e += 256) {
        int dst = edges[e];
        int src = edges[N_EDGES + e];
        int b = dst >> SH;
        int pos = atomicAdd(&cur[b], 1);
        packed[pos] = (src << SH) | (dst & (BSZ - 1));
    }
}

// Level 2: one block per bucket. LDS hist over 512 local nodes + scan gives
// exact per-node CSR offsets/deg; then scatter srcs into the bucket's
// contiguous sortedSrc span.
__global__ __launch_bounds__(256) void bucket_csr(const int* __restrict__ packed,
                                                  const int* __restrict__ bbase,
                                                  const int* __restrict__ colsum,
                                                  int* __restrict__ offsets,
                                                  int* __restrict__ deg,
                                                  int* __restrict__ srt)
{
    __shared__ int h2[BSZ];
    __shared__ int cur2[BSZ];
    __shared__ int s[256];
    const int b = blockIdx.x;
    const int t = threadIdx.x;
    const int start = bbase[b];
    const int cnt   = colsum[b];

    for (int i = t; i < BSZ; i += 256) h2[i] = 0;
    __syncthreads();
    for (int i = t; i < cnt; i += 256)
        atomicAdd(&h2[packed[start + i] & (BSZ - 1)], 1);
    __syncthreads();

    // exclusive scan of 512 via pair-scan with 256 threads
    int a0 = h2[2 * t], a1 = h2[2 * t + 1];
    int pair = a0 + a1;
    s[t] = pair; __syncthreads();
    for (int o = 1; o < 256; o <<= 1) {
        int u = (t >= o) ? s[t - o] : 0;
        __syncthreads();
        s[t] += u;
        __syncthreads();
    }
    int excl = s[t] - pair;

    const int node0 = (b << SH) + 2 * t;
    if (node0 < N_NODES)     { offsets[node0]     = start + excl;      deg[node0]     = a0; }
    if (node0 + 1 < N_NODES) { offsets[node0 + 1] = start + excl + a0; deg[node0 + 1] = a1; }
    cur2[2 * t]     = excl;
    cur2[2 * t + 1] = excl + a0;
    __syncthreads();

    for (int i = t; i < cnt; i += 256) {
        int p = packed[start + i];
        int l = p & (BSZ - 1);
        int r = atomicAdd(&cur2[l], 1);
        srt[start + r] = p >> SH;
    }
}

// ---------------------------------------------------------------------------
// mid tier: round-0 proven pipeline (node-level hist + scans + scatter_idx)
// ---------------------------------------------------------------------------

__global__ __launch_bounds__(256) void hist_kernel(const int* __restrict__ edges,
                                                   int* __restrict__ deg)
{
    int e = blockIdx.x * 256 + threadIdx.x;
    if (e < N_EDGES) atomicAdd(&deg[edges[e]], 1);
}

__global__ __launch_bounds__(256) void scan_part(const int* __restrict__ deg,
                                                 int* __restrict__ partial)
{
    int t = threadIdx.x;
    int base = blockIdx.x * SCAN_CHUNK + t * 4;
    int s = 0;
    #pragma unroll
    for (int k = 0; k < 4; ++k) { int i = base + k; if (i < N_NODES) s += deg[i]; }
    int lane = t & 63, wid = t >> 6;
    #pragma unroll
    for (int off = 32; off; off >>= 1) s += __shfl_down(s, off, 64);
    __shared__ int red[4];
    if (lane == 0) red[wid] = s;
    __syncthreads();
    if (t == 0) partial[blockIdx.x] = red[0] + red[1] + red[2] + red[3];
}

__device__ __forceinline__ int waveInclScan(int v, int lane) {
    #pragma unroll
    for (int off = 1; off < 64; off <<= 1) {
        int t = __shfl_up(v, off, 64);
        if (lane >= off) v += t;
    }
    return v;
}

__global__ void scan_small(int* partial) {
    int lane = threadIdx.x;
    int v0 = (lane < NCHUNK) ? partial[lane] : 0;
    int v1 = (64 + lane < NCHUNK) ? partial[64 + lane] : 0;
    int i0 = waveInclScan(v0, lane);
    int tot0 = __shfl(i0, 63, 64);
    int i1 = waveInclScan(v1, lane) + tot0;
    if (lane < NCHUNK) partial[lane] = i0 - v0;
    if (64 + lane < NCHUNK) partial[64 + lane] = i1 - v1;
}

__global__ __launch_bounds__(256) void scan_final(const int* __restrict__ deg,
                                                  const int* __restrict__ partial,
                                                  int* __restrict__ offsets,
                                                  int* __restrict__ cursor)
{
    int t = threadIdx.x;
    int base = blockIdx.x * SCAN_CHUNK + t * 4;
    int d[4]; int s = 0;
    #pragma unroll
    for (int k = 0; k < 4; ++k) { int i = base + k; d[k] = (i < N_NODES) ? deg[i] : 0; s += d[k]; }
    __shared__ int sd[256];
    sd[t] = s; __syncthreads();
    #pragma unroll
    for (int off = 1; off < 256; off <<= 1) {
        int v = (t >= off) ? sd[t - off] : 0;
        __syncthreads();
        sd[t] += v;
        __syncthreads();
    }
    int excl = sd[t] - s + partial[blockIdx.x];
    #pragma unroll
    for (int k = 0; k < 4; ++k) {
        int i = base + k;
        if (i < N_NODES) { offsets[i] = excl; cursor[i] = excl; excl += d[k]; }
    }
}

__global__ __launch_bounds__(256) void scatter_idx(const int* __restrict__ edges,
                                                   int* __restrict__ cursor,
                                                   int* __restrict__ sortedSrc)
{
    int e = blockIdx.x * 256 + threadIdx.x;
    if (e >= N_EDGES) return;
    int dst = edges[e];
    int src = edges[N_EDGES + e];
    int pos = atomicAdd(&cursor[dst], 1);
    sortedSrc[pos] = src;
}

// ---------------------------------------------------------------------------
// last-resort fallback (round-1, proven)
// ---------------------------------------------------------------------------

__global__ __launch_bounds__(256) void fb_scatter(
    const float* __restrict__ vertices, const int* __restrict__ edges,
    float* __restrict__ agg, float* __restrict__ degF)
{
    long long tid = (long long)blockIdx.x * 256 + threadIdx.x;
    int lane = threadIdx.x & 63;
    long long e = tid >> 6;
    if (e >= N_EDGES) return;
    int dst = edges[e];
    int src = edges[N_EDGES + e];
    atomicAdd(&agg[(size_t)dst * D + lane], vertices[(size_t)src * D + lane]);
    if (lane == 0) atomicAdd(&degF[dst], 1.0f);
}

__global__ __launch_bounds__(256) void fb_finish(
    const float* __restrict__ vertices, const float* __restrict__ weight,
    const float* __restrict__ bias, const float* __restrict__ degF,
    float* __restrict__ out)
{
    __shared__ float rowbuf[4][64];
    const int wid  = threadIdx.x >> 6;
    const int lane = threadIdx.x & 63;
    float w[64];
    #pragma unroll
    for (int f = 0; f < 64; ++f) w[f] = weight[lane * 64 + f];
    const float b = bias[lane];
    const int nodesPerIter = gridDim.x * 4;
    for (int base = blockIdx.x * 4; base < N_NODES; base += nodesPerIter) {
        const int node = base + wid;
        float a = 0.0f;
        if (node < N_NODES) {
            const float scale = rsqrtf(degF[node] + 1.0f);
            a = (out[(size_t)node * D + lane] + vertices[(size_t)node * D + lane]) * scale;
        }
        rowbuf[wid][lane] = a;
        __syncthreads();
        float acc = b;
        #pragma unroll
        for (int f = 0; f < 64; ++f) acc += rowbuf[wid][f] * w[f];
        if (node < N_NODES) out[(size_t)node * D + lane] = acc;
        __syncthreads();
    }
}

extern "C" void kernel_launch(void* const* d_in, const int* in_sizes, int n_in,
                              void* d_out, int out_size, void* d_ws, size_t ws_size,
                              hipStream_t stream) {
    const float* vertices = (const float*)d_in[0];
    const int*   edges    = (const int*)d_in[1];
    const float* weight   = (const float*)d_in[2];
    const float* bias     = (const float*)d_in[3];
    float* out = (float*)d_out;

    const int threads = 256;
    const int edgeBlocks = (N_EDGES + threads - 1) / threads;

    // --- fast layout: Y | H[SPLITB*NB] | colsum | bbase | offsets | deg | packed | srt
    {
        float* Y      = (float*)d_ws;
        int*   H      = (int*)(Y + (size_t)N_NODES * D);
        int*   colsum = H + SPLITB * NB;
        int*   bbase  = colsum + NB;
        int*   offs   = bbase + NB;
        int*   deg    = offs + N_NODES;
        int*   packed = deg + N_NODES;
        int*   srt    = packed + N_EDGES;
        size_t needed = (size_t)((char*)(srt + N_EDGES) - (char*)d_ws);
        if (ws_size >= needed) {
            linear_kernel<<<1024, threads, 0, stream>>>(vertices, weight, Y);
            s_hist<<<SPLITB, threads, 0, stream>>>(edges, H);
            s_scanA<<<NB, threads, 0, stream>>>(H, colsum);
            s_scanB<<<1, threads, 0, stream>>>(colsum, bbase);
            s_scatter<<<SPLITB, threads, 0, stream>>>(edges, H, bbase, packed);
            bucket_csr<<<NB, threads, 0, stream>>>(packed, bbase, colsum, offs, deg, srt);
            gather_kernel<<<(N_NODES + 3) / 4, threads, 0, stream>>>(Y, offs, deg, srt, bias, out);
            return;
        }
    }

    // --- mid layout (round-0 proven): Y | deg | offsets | cursor | partial[128] | srt
    {
        float* Y       = (float*)d_ws;
        int*   deg     = (int*)(Y + (size_t)N_NODES * D);
        int*   offs    = deg + N_NODES;
        int*   cursor  = offs + N_NODES;
        int*   partial = cursor + N_NODES;
        int*   srt     = partial + 128;
        size_t needed  = (size_t)((char*)(srt + N_EDGES) - (char*)d_ws);
        if (ws_size >= needed) {
            hipMemsetAsync(deg, 0, sizeof(int) * N_NODES, stream);
            linear_kernel<<<1024, threads, 0, stream>>>(vertices, weight, Y);
            hist_kernel<<<edgeBlocks, threads, 0, stream>>>(edges, deg);
            scan_part<<<NCHUNK, threads, 0, stream>>>(deg, partial);
            scan_small<<<1, 64, 0, stream>>>(partial);
            scan_final<<<NCHUNK, threads, 0, stream>>>(deg, partial, offs, cursor);
            scatter_idx<<<edgeBlocks, threads, 0, stream>>>(edges, cursor, srt);
            gather_kernel<<<(N_NODES + 3) / 4, threads, 0, stream>>>(Y, offs, deg, srt, bias, out);
            return;
        }
    }

    // --- last resort
    {
        float* degF = (float*)d_ws;
        hipMemsetAsync(out, 0, sizeof(float) * (size_t)N_NODES * D, stream);
        hipMemsetAsync(degF, 0, sizeof(float) * N_NODES, stream);
        const long long totalScatter = (long long)N_EDGES * 64;
        fb_scatter<<<(int)((totalScatter + threads - 1) / threads), threads, 0, stream>>>(
            vertices, edges, out, degF);
        fb_finish<<<1024, threads, 0, stream>>>(vertices, weight, bias, degF, out);
    }
}

// Round 3
// 142.085 us; speedup vs baseline: 6.4305x; 1.0706x over previous
//
#include <hip/hip_runtime.h>

constexpr int N_NODES = 100000;
constexpr int N_EDGES = 1600000;
constexpr int D = 64;

// ---- deterministic two-level split parameters ----
constexpr int SH     = 9;                                  // 512 nodes / bucket
constexpr int BSZ    = 1 << SH;                            // 512
constexpr int NB     = (N_NODES + BSZ - 1) / BSZ;          // 196 buckets
constexpr int SPLITB = 256;                                // split grid blocks
constexpr int TILE   = (N_EDGES + SPLITB - 1) / SPLITB;    // 6250 edges / block
constexpr int LINB   = 2048;                               // linear blocks in fused front

// ---- mid-tier (round-0 proven) scan parameters ----
constexpr int SCAN_CHUNK = 1024;
constexpr int NCHUNK = (N_NODES + SCAN_CHUNK - 1) / SCAN_CHUNK;   // 98

// ---------------------------------------------------------------------------
// fused front: blocks [0,LINB) do Y = X @ W^T, blocks [LINB,LINB+SPLITB) do
// the per-tile bucket histogram. Independent work, one dispatch.
// ---------------------------------------------------------------------------
__global__ __launch_bounds__(256) void lin_hist(
    const float* __restrict__ vertices,
    const float* __restrict__ weight,   // [64][64] row-major
    float* __restrict__ Y,
    const int* __restrict__ edges,
    int* __restrict__ H)
{
    __shared__ float smem[4 * 64];      // linear: rowbuf[4][64]; hist: int h[NB]

    if (blockIdx.x < LINB) {
        float (*rowbuf)[64] = (float (*)[64])smem;
        const int wid  = threadIdx.x >> 6;
        const int lane = threadIdx.x & 63;

        float w[64];
        #pragma unroll
        for (int f = 0; f < 64; ++f) w[f] = weight[lane * 64 + f];

        const int nodesPerIter = LINB * 4;
        for (int base = blockIdx.x * 4; base < N_NODES; base += nodesPerIter) {
            const int node = base + wid;
            float a = 0.0f;
            if (node < N_NODES) a = vertices[(size_t)node * D + lane];
            rowbuf[wid][lane] = a;
            __syncthreads();
            float acc = 0.0f;
            #pragma unroll
            for (int f = 0; f < 64; ++f)
                acc += rowbuf[wid][f] * w[f];       // same-address broadcast
            if (node < N_NODES) Y[(size_t)node * D + lane] = acc;
            __syncthreads();
        }
    } else {
        int* h = (int*)smem;
        const int b = blockIdx.x - LINB;
        for (int i = threadIdx.x; i < NB; i += 256) h[i] = 0;
        __syncthreads();
        const int lo = b * TILE;
        const int hi = min(lo + TILE, N_EDGES);
        for (int e = lo + threadIdx.x; e < hi; e += 256)
            atomicAdd(&h[edges[e] >> SH], 1);
        __syncthreads();
        for (int i = threadIdx.x; i < NB; i += 256)
            H[b * NB + i] = h[i];
    }
}

// Scan A: one block per bucket; exclusive-scan its column of H (SPLITB rows),
// leave exclusive values in place, emit column total.
__global__ __launch_bounds__(256) void s_scanA(int* __restrict__ H,
                                               int* __restrict__ colsum)
{
    const int j = blockIdx.x;
    const int t = threadIdx.x;
    int v = H[t * NB + j];
    __shared__ int s[256];
    s[t] = v; __syncthreads();
    for (int o = 1; o < 256; o <<= 1) {
        int u = (t >= o) ? s[t - o] : 0;
        __syncthreads();
        s[t] += u;
        __syncthreads();
    }
    H[t * NB + j] = s[t] - v;            // exclusive within column
    if (t == 255) colsum[j] = s[t];
}

// Pass 2: re-read edges; every block rebuilds the 196-wide bucket-base scan in
// LDS (replaces the old s_scanB dispatch), seeds cursors with its deterministic
// per-(block,bucket) offset, writes packed (src<<9 | dst&511).
__global__ __launch_bounds__(256) void s_scatter(const int* __restrict__ edges,
                                                 const int* __restrict__ H,
                                                 const int* __restrict__ colsum,
                                                 int* __restrict__ packed)
{
    __shared__ int cur[NB];
    __shared__ int s[256];
    const int t = threadIdx.x;
    int v = (t < NB) ? colsum[t] : 0;
    s[t] = v; __syncthreads();
    for (int o = 1; o < 256; o <<= 1) {
        int u = (t >= o) ? s[t - o] : 0;
        __syncthreads();
        s[t] += u;
        __syncthreads();
    }
    if (t < NB) cur[t] = (s[t] - v) + H[blockIdx.x * NB + t];
    __syncthreads();

    const int lo = blockIdx.x * TILE;
    const int hi = min(lo + TILE, N_EDGES);
    for (int e = lo + t; e < hi; e += 256) {
        int dst = edges[e];
        int src = edges[N_EDGES + e];
        int b = dst >> SH;
        int pos = atomicAdd(&cur[b], 1);
        packed[pos] = (src << SH) | (dst & (BSZ - 1));
    }
}

// Level 2: one block per bucket. LDS hist over 512 local nodes + scan gives
// exact per-node CSR offsets/deg; then scatter srcs into the bucket's
// contiguous sortedSrc span. Bucket base recomputed in LDS from colsum.
__global__ __launch_bounds__(256) void bucket_csr(const int* __restrict__ packed,
                                                  const int* __restrict__ colsum,
                                                  int* __restrict__ offsets,
                                                  int* __restrict__ deg,
                                                  int* __restrict__ srt)
{
    __shared__ int h2[BSZ];
    __shared__ int cur2[BSZ];
    __shared__ int s[256];
    __shared__ int s_start;
    const int b = blockIdx.x;
    const int t = threadIdx.x;

    for (int i = t; i < BSZ; i += 256) h2[i] = 0;
    int v = (t < NB) ? colsum[t] : 0;
    s[t] = v; __syncthreads();
    for (int o = 1; o < 256; o <<= 1) {
        int u = (t >= o) ? s[t - o] : 0;
        __syncthreads();
        s[t] += u;
        __syncthreads();
    }
    if (t == b) s_start = s[t] - v;
    __syncthreads();
    const int start = s_start;
    const int cnt   = colsum[b];

    for (int i = t; i < cnt; i += 256)
        atomicAdd(&h2[packed[start + i] & (BSZ - 1)], 1);
    __syncthreads();

    // exclusive scan of 512 via pair-scan with 256 threads
    int a0 = h2[2 * t], a1 = h2[2 * t + 1];
    int pair = a0 + a1;
    s[t] = pair; __syncthreads();
    for (int o = 1; o < 256; o <<= 1) {
        int u = (t >= o) ? s[t - o] : 0;
        __syncthreads();
        s[t] += u;
        __syncthreads();
    }
    int excl = s[t] - pair;

    const int node0 = (b << SH) + 2 * t;
    if (node0 < N_NODES)     { offsets[node0]     = start + excl;      deg[node0]     = a0; }
    if (node0 + 1 < N_NODES) { offsets[node0 + 1] = start + excl + a0; deg[node0 + 1] = a1; }
    cur2[2 * t]     = excl;
    cur2[2 * t + 1] = excl + a0;
    __syncthreads();

    for (int i = t; i < cnt; i += 256) {
        int p = packed[start + i];
        int l = p & (BSZ - 1);
        int r = atomicAdd(&cur2[l], 1);
        srt[start + r] = p >> SH;
    }
}

// ---------------------------------------------------------------------------
// gather: one wave per node, 4x16-lane groups. Each group loads a full 256B
// Y row as 16 lanes x dwordx4 -> ONE wave64 VMEM instruction covers 4 edges
// (vs 4 before). Cross-group float4 partials reduced with shfl_xor(16,32).
// ---------------------------------------------------------------------------
__global__ __launch_bounds__(256) void gather_kernel(
    const float* __restrict__ Y,
    const int* __restrict__ offsets,
    const int* __restrict__ deg,
    const int* __restrict__ sortedSrc,
    const float* __restrict__ bias,
    float* __restrict__ out)
{
    const int wid  = threadIdx.x >> 6;
    const int lane = threadIdx.x & 63;
    const int g    = lane >> 4;          // edge slot within quad
    const int sub  = lane & 15;          // float4 column index
    const int node = blockIdx.x * 4 + wid;
    if (node >= N_NODES) return;

    const int start = offsets[node];
    const int cnt   = deg[node];

    float4 acc;
    if (g == 0) {
        acc = *reinterpret_cast<const float4*>(Y + (size_t)node * D + (sub << 2)); // self loop
    } else {
        acc.x = 0.0f; acc.y = 0.0f; acc.z = 0.0f; acc.w = 0.0f;
    }

    int e = 0;
    for (; e + 8 <= cnt; e += 8) {
        int s0 = sortedSrc[start + e + g];
        int s1 = sortedSrc[start + e + 4 + g];
        const float4 a0 = *reinterpret_cast<const float4*>(Y + (size_t)s0 * D + (sub << 2));
        const float4 a1 = *reinterpret_cast<const float4*>(Y + (size_t)s1 * D + (sub << 2));
        acc.x += a0.x; acc.y += a0.y; acc.z += a0.z; acc.w += a0.w;
        acc.x += a1.x; acc.y += a1.y; acc.z += a1.z; acc.w += a1.w;
    }
    if (e + 4 <= cnt) {
        int s0 = sortedSrc[start + e + g];
        const float4 a0 = *reinterpret_cast<const float4*>(Y + (size_t)s0 * D + (sub << 2));
        acc.x += a0.x; acc.y += a0.y; acc.z += a0.z; acc.w += a0.w;
        e += 4;
    }
    if (e + g < cnt) {
        int s0 = sortedSrc[start + e + g];
        const float4 a0 = *reinterpret_cast<const float4*>(Y + (size_t)s0 * D + (sub << 2));
        acc.x += a0.x; acc.y += a0.y; acc.z += a0.z; acc.w += a0.w;
    }

    // sum the 4 group partials (columns align across groups)
    acc.x += __shfl_xor(acc.x, 16, 64);
    acc.y += __shfl_xor(acc.y, 16, 64);
    acc.z += __shfl_xor(acc.z, 16, 64);
    acc.w += __shfl_xor(acc.w, 16, 64);
    acc.x += __shfl_xor(acc.x, 32, 64);
    acc.y += __shfl_xor(acc.y, 32, 64);
    acc.z += __shfl_xor(acc.z, 32, 64);
    acc.w += __shfl_xor(acc.w, 32, 64);

    if (lane < 16) {
        const float sc = rsqrtf((float)cnt + 1.0f);
        const float4 b4 = *reinterpret_cast<const float4*>(bias + (sub << 2));
        float4 r;
        r.x = acc.x * sc + b4.x;
        r.y = acc.y * sc + b4.y;
        r.z = acc.z * sc + b4.z;
        r.w = acc.w * sc + b4.w;
        *reinterpret_cast<float4*>(out + (size_t)node * D + (sub << 2)) = r;
    }
}

// ---------------------------------------------------------------------------
// mid tier: round-0 proven pipeline (node-level hist + scans + scatter_idx)
// ---------------------------------------------------------------------------

__global__ __launch_bounds__(256) void linear_kernel(
    const float* __restrict__ vertices,
    const float* __restrict__ weight,
    float* __restrict__ Y)
{
    __shared__ float rowbuf[4][64];
    const int wid  = threadIdx.x >> 6;
    const int lane = threadIdx.x & 63;
    float w[64];
    #pragma unroll
    for (int f = 0; f < 64; ++f) w[f] = weight[lane * 64 + f];
    const int nodesPerIter = gridDim.x * 4;
    for (int base = blockIdx.x * 4; base < N_NODES; base += nodesPerIter) {
        const int node = base + wid;
        float a = 0.0f;
        if (node < N_NODES) a = vertices[(size_t)node * D + lane];
        rowbuf[wid][lane] = a;
        __syncthreads();
        float acc = 0.0f;
        #pragma unroll
        for (int f = 0; f < 64; ++f)
            acc += rowbuf[wid][f] * w[f];
        if (node < N_NODES) Y[(size_t)node * D + lane] = acc;
        __syncthreads();
    }
}

__global__ __launch_bounds__(256) void hist_kernel(const int* __restrict__ edges,
                                                   int* __restrict__ deg)
{
    int e = blockIdx.x * 256 + threadIdx.x;
    if (e < N_EDGES) atomicAdd(&deg[edges[e]], 1);
}

__global__ __launch_bounds__(256) void scan_part(const int* __restrict__ deg,
                                                 int* __restrict__ partial)
{
    int t = threadIdx.x;
    int base = blockIdx.x * SCAN_CHUNK + t * 4;
    int s = 0;
    #pragma unroll
    for (int k = 0; k < 4; ++k) { int i = base + k; if (i < N_NODES) s += deg[i]; }
    int lane = t & 63, wid = t >> 6;
    #pragma unroll
    for (int off = 32; off; off >>= 1) s += __shfl_down(s, off, 64);
    __shared__ int red[4];
    if (lane == 0) red[wid] = s;
    __syncthreads();
    if (t == 0) partial[blockIdx.x] = red[0] + red[1] + red[2] + red[3];
}

__device__ __forceinline__ int waveInclScan(int v, int lane) {
    #pragma unroll
    for (int off = 1; off < 64; off <<= 1) {
        int t = __shfl_up(v, off, 64);
        if (lane >= off) v += t;
    }
    return v;
}

__global__ void scan_small(int* partial) {
    int lane = threadIdx.x;
    int v0 = (lane < NCHUNK) ? partial[lane] : 0;
    int v1 = (64 + lane < NCHUNK) ? partial[64 + lane] : 0;
    int i0 = waveInclScan(v0, lane);
    int tot0 = __shfl(i0, 63, 64);
    int i1 = waveInclScan(v1, lane) + tot0;
    if (lane < NCHUNK) partial[lane] = i0 - v0;
    if (64 + lane < NCHUNK) partial[64 + lane] = i1 - v1;
}

__global__ __launch_bounds__(256) void scan_final(const int* __restrict__ deg,
                                                  const int* __restrict__ partial,
                                                  int* __restrict__ offsets,
                                                  int* __restrict__ cursor)
{
    int t = threadIdx.x;
    int base = blockIdx.x * SCAN_CHUNK + t * 4;
    int d[4]; int s = 0;
    #pragma unroll
    for (int k = 0; k < 4; ++k) { int i = base + k; d[k] = (i < N_NODES) ? deg[i] : 0; s += d[k]; }
    __shared__ int sd[256];
    sd[t] = s; __syncthreads();
    #pragma unroll
    for (int off = 1; off < 256; off <<= 1) {
        int v = (t >= off) ? sd[t - off] : 0;
        __syncthreads();
        sd[t] += v;
        __syncthreads();
    }
    int excl = sd[t] - s + partial[blockIdx.x];
    #pragma unroll
    for (int k = 0; k < 4; ++k) {
        int i = base + k;
        if (i < N_NODES) { offsets[i] = excl; cursor[i] = excl; excl += d[k]; }
    }
}

__global__ __launch_bounds__(256) void scatter_idx(const int* __restrict__ edges,
                                                   int* __restrict__ cursor,
                                                   int* __restrict__ sortedSrc)
{
    int e = blockIdx.x * 256 + threadIdx.x;
    if (e >= N_EDGES) return;
    int dst = edges[e];
    int src = edges[N_EDGES + e];
    int pos = atomicAdd(&cursor[dst], 1);
    sortedSrc[pos] = src;
}

// ---------------------------------------------------------------------------
// last-resort fallback (round-1, proven)
// ---------------------------------------------------------------------------

__global__ __launch_bounds__(256) void fb_scatter(
    const float* __restrict__ vertices, const int* __restrict__ edges,
    float* __restrict__ agg, float* __restrict__ degF)
{
    long long tid = (long long)blockIdx.x * 256 + threadIdx.x;
    int lane = threadIdx.x & 63;
    long long e = tid >> 6;
    if (e >= N_EDGES) return;
    int dst = edges[e];
    int src = edges[N_EDGES + e];
    atomicAdd(&agg[(size_t)dst * D + lane], vertices[(size_t)src * D + lane]);
    if (lane == 0) atomicAdd(&degF[dst], 1.0f);
}

__global__ __launch_bounds__(256) void fb_finish(
    const float* __restrict__ vertices, const float* __restrict__ weight,
    const float* __restrict__ bias, const float* __restrict__ degF,
    float* __restrict__ out)
{
    __shared__ float rowbuf[4][64];
    const int wid  = threadIdx.x >> 6;
    const int lane = threadIdx.x & 63;
    float w[64];
    #pragma unroll
    for (int f = 0; f < 64; ++f) w[f] = weight[lane * 64 + f];
    const float b = bias[lane];
    const int nodesPerIter = gridDim.x * 4;
    for (int base = blockIdx.x * 4; base < N_NODES; base += nodesPerIter) {
        const int node = base + wid;
        float a = 0.0f;
        if (node < N_NODES) {
            const float scale = rsqrtf(degF[node] + 1.0f);
            a = (out[(size_t)node * D + lane] + vertices[(size_t)node * D + lane]) * scale;
        }
        rowbuf[wid][lane] = a;
        __syncthreads();
        float acc = b;
        #pragma unroll
        for (int f = 0; f < 64; ++f) acc += rowbuf[wid][f] * w[f];
        if (node < N_NODES) out[(size_t)node * D + lane] = acc;
        __syncthreads();
    }
}

extern "C" void kernel_launch(void* const* d_in, const int* in_sizes, int n_in,
                              void* d_out, int out_size, void* d_ws, size_t ws_size,
                              hipStream_t stream) {
    const float* vertices = (const float*)d_in[0];
    const int*   edges    = (const int*)d_in[1];
    const float* weight   = (const float*)d_in[2];
    const float* bias     = (const float*)d_in[3];
    float* out = (float*)d_out;

    const int threads = 256;
    const int edgeBlocks = (N_EDGES + threads - 1) / threads;

    // --- fast layout: Y | H[SPLITB*NB] | colsum | offsets | deg | packed | srt
    {
        float* Y      = (float*)d_ws;
        int*   H      = (int*)(Y + (size_t)N_NODES * D);
        int*   colsum = H + SPLITB * NB;
        int*   offs   = colsum + NB;
        int*   deg    = offs + N_NODES;
        int*   packed = deg + N_NODES;
        int*   srt    = packed + N_EDGES;
        size_t needed = (size_t)((char*)(srt + N_EDGES) - (char*)d_ws);
        if (ws_size >= needed) {
            lin_hist<<<LINB + SPLITB, threads, 0, stream>>>(vertices, weight, Y, edges, H);
            s_scanA<<<NB, threads, 0, stream>>>(H, colsum);
            s_scatter<<<SPLITB, threads, 0, stream>>>(edges, H, colsum, packed);
            bucket_csr<<<NB, threads, 0, stream>>>(packed, colsum, offs, deg, srt);
            gather_kernel<<<(N_NODES + 3) / 4, threads, 0, stream>>>(Y, offs, deg, srt, bias, out);
            return;
        }
    }

    // --- mid layout (round-0 proven): Y | deg | offsets | cursor | partial[128] | srt
    {
        float* Y       = (float*)d_ws;
        int*   deg     = (int*)(Y + (size_t)N_NODES * D);
        int*   offs    = deg + N_NODES;
        int*   cursor  = offs + N_NODES;
        int*   partial = cursor + N_NODES;
        int*   srt     = partial + 128;
        size_t needed  = (size_t)((char*)(srt + N_EDGES) - (char*)d_ws);
        if (ws_size >= needed) {
            hipMemsetAsync(deg, 0, sizeof(int) * N_NODES, stream);
            linear_kernel<<<1024, threads, 0, stream>>>(vertices, weight, Y);
            hist_kernel<<<edgeBlocks, threads, 0, stream>>>(edges, deg);
            scan_part<<<NCHUNK, threads, 0, stream>>>(deg, partial);
            scan_small<<<1, 64, 0, stream>>>(partial);
            scan_final<<<NCHUNK, threads, 0, stream>>>(deg, partial, offs, cursor);
            scatter_idx<<<edgeBlocks, threads, 0, stream>>>(edges, cursor, srt);
            gather_kernel<<<(N_NODES + 3) / 4, threads, 0, stream>>>(Y, offs, deg, srt, bias, out);
            return;
        }
    }

    // --- last resort
    {
        float* degF = (float*)d_ws;
        hipMemsetAsync(out, 0, sizeof(float) * (size_t)N_NODES * D, stream);
        hipMemsetAsync(degF, 0, sizeof(float) * N_NODES, stream);
        const long long totalScatter = (long long)N_EDGES * 64;
        fb_scatter<<<(int)((totalScatter + threads - 1) / threads), threads, 0, stream>>>(
            vertices, edges, out, degF);
        fb_finish<<<1024, threads, 0, stream>>>(vertices, weight, bias, degF, out);
    }
}

// Round 4
// 116.221 us; speedup vs baseline: 7.8616x; 1.2225x over previous
//
#include <hip/hip_runtime.h>
#include <hip/hip_fp16.h>

constexpr int N_NODES = 100000;
constexpr int N_EDGES = 1600000;
constexpr int D = 64;

// ---- deterministic two-level split parameters ----
constexpr int SH2    = 7;                                  // 128 nodes / bucket
constexpr int BSZ    = 1 << SH2;                           // 128
constexpr int NB     = (N_NODES + BSZ - 1) / BSZ;          // 782 buckets
constexpr int SPLITB = 256;                                // split grid blocks
constexpr int TILE   = (N_EDGES + SPLITB - 1) / SPLITB;    // 6250 edges / block
constexpr int LINB   = 2048;                               // linear blocks in fused front

// ---- mid-tier (round-0 proven) scan parameters ----
constexpr int SCAN_CHUNK = 1024;
constexpr int NCHUNK = (N_NODES + SCAN_CHUNK - 1) / SCAN_CHUNK;   // 98

// ---------------------------------------------------------------------------
// fused front: blocks [0,LINB) do Yh = fp16(X @ W^T), blocks [LINB,LINB+SPLITB)
// do the per-tile bucket histogram. Independent work, one dispatch.
// ---------------------------------------------------------------------------
__global__ __launch_bounds__(256) void lin_hist(
    const float* __restrict__ vertices,
    const float* __restrict__ weight,   // [64][64] row-major
    __half* __restrict__ Yh,
    const int* __restrict__ edges,
    int* __restrict__ H)
{
    if (blockIdx.x < LINB) {
        __shared__ float rowbuf[4][64];
        const int wid  = threadIdx.x >> 6;
        const int lane = threadIdx.x & 63;

        float w[64];
        #pragma unroll
        for (int f = 0; f < 64; ++f) w[f] = weight[lane * 64 + f];

        const int nodesPerIter = LINB * 4;
        for (int base = blockIdx.x * 4; base < N_NODES; base += nodesPerIter) {
            const int node = base + wid;
            float a = 0.0f;
            if (node < N_NODES) a = vertices[(size_t)node * D + lane];
            rowbuf[wid][lane] = a;
            __syncthreads();
            float acc = 0.0f;
            #pragma unroll
            for (int f = 0; f < 64; ++f)
                acc += rowbuf[wid][f] * w[f];       // same-address broadcast
            if (node < N_NODES) Yh[(size_t)node * D + lane] = __float2half(acc);
            __syncthreads();
        }
    } else {
        __shared__ int h[NB];
        const int b = blockIdx.x - LINB;
        for (int i = threadIdx.x; i < NB; i += 256) h[i] = 0;
        __syncthreads();
        const int lo = b * TILE;
        const int hi = min(lo + TILE, N_EDGES);
        for (int e = lo + threadIdx.x; e < hi; e += 256)
            atomicAdd(&h[edges[e] >> SH2], 1);
        __syncthreads();
        for (int i = threadIdx.x; i < NB; i += 256)
            H[b * NB + i] = h[i];
    }
}

// Scan A: one block per bucket; exclusive-scan its column of H (SPLITB rows),
// leave exclusive values in place, emit column total.
__global__ __launch_bounds__(256) void s_scanA(int* __restrict__ H,
                                               int* __restrict__ colsum)
{
    const int j = blockIdx.x;
    const int t = threadIdx.x;
    int v = H[t * NB + j];
    __shared__ int s[256];
    s[t] = v; __syncthreads();
    for (int o = 1; o < 256; o <<= 1) {
        int u = (t >= o) ? s[t - o] : 0;
        __syncthreads();
        s[t] += u;
        __syncthreads();
    }
    H[t * NB + j] = s[t] - v;            // exclusive within column
    if (t == 255) colsum[j] = s[t];
}

// Scan B: exclusive scan of the NB (782) column totals, 4 elems/thread.
__global__ void s_scanB(const int* __restrict__ colsum, int* __restrict__ bbase)
{
    __shared__ int s[256];
    const int t = threadIdx.x;
    int v[4]; int loc = 0;
    #pragma unroll
    for (int k = 0; k < 4; ++k) {
        int i = t * 4 + k;
        v[k] = (i < NB) ? colsum[i] : 0;
        loc += v[k];
    }
    s[t] = loc; __syncthreads();
    for (int o = 1; o < 256; o <<= 1) {
        int u = (t >= o) ? s[t - o] : 0;
        __syncthreads();
        s[t] += u;
        __syncthreads();
    }
    int excl = s[t] - loc;
    #pragma unroll
    for (int k = 0; k < 4; ++k) {
        int i = t * 4 + k;
        if (i < NB) bbase[i] = excl;
        excl += v[k];
    }
}

// Pass 2: re-read edges; seed LDS cursors with the deterministic global
// (block,bucket) offset; write packed (src<<7 | dst&127).
__global__ __launch_bounds__(256) void s_scatter(const int* __restrict__ edges,
                                                 const int* __restrict__ H,
                                                 const int* __restrict__ bbase,
                                                 int* __restrict__ packed)
{
    __shared__ int cur[NB];
    for (int i = threadIdx.x; i < NB; i += 256)
        cur[i] = bbase[i] + H[blockIdx.x * NB + i];
    __syncthreads();
    const int lo = blockIdx.x * TILE;
    const int hi = min(lo + TILE, N_EDGES);
    for (int e = lo + threadIdx.x; e < hi; e += 256) {
        int dst = edges[e];
        int src = edges[N_EDGES + e];
        int pos = atomicAdd(&cur[dst >> SH2], 1);
        packed[pos] = (src << SH2) | (dst & (BSZ - 1));
    }
}

// Level 2: one block per bucket (782 blocks). LDS hist over 128 local nodes +
// scan -> exact CSR offsets/deg; scatter srcs into the bucket's srt span.
__global__ __launch_bounds__(256) void bucket_csr(const int* __restrict__ packed,
                                                  const int* __restrict__ bbase,
                                                  const int* __restrict__ colsum,
                                                  int* __restrict__ offsets,
                                                  int* __restrict__ deg,
                                                  int* __restrict__ srt)
{
    __shared__ int h2[BSZ];
    __shared__ int cur2[BSZ];
    __shared__ int s[BSZ];
    const int b = blockIdx.x;
    const int t = threadIdx.x;
    const int start = bbase[b];
    const int cnt   = colsum[b];

    if (t < BSZ) h2[t] = 0;
    __syncthreads();
    for (int i = t; i < cnt; i += 256)
        atomicAdd(&h2[packed[start + i] & (BSZ - 1)], 1);
    __syncthreads();

    if (t < BSZ) s[t] = h2[t];
    __syncthreads();
    for (int o = 1; o < BSZ; o <<= 1) {
        int u = (t >= o && t < BSZ) ? s[t - o] : 0;
        __syncthreads();
        if (t < BSZ) s[t] += u;
        __syncthreads();
    }
    if (t < BSZ) {
        int excl = s[t] - h2[t];
        int node = (b << SH2) + t;
        if (node < N_NODES) { offsets[node] = start + excl; deg[node] = h2[t]; }
        cur2[t] = excl;
    }
    __syncthreads();

    for (int i = t; i < cnt; i += 256) {
        int p = packed[start + i];
        int r = atomicAdd(&cur2[p & (BSZ - 1)], 1);
        srt[start + r] = p >> SH2;
    }
}

// ---------------------------------------------------------------------------
// gather: one wave per node, 8x8-lane groups. Each group loads a full 128B
// fp16 row as 8 lanes x dwordx4 -> ONE wave64 VMEM instruction covers 8 rows.
// fp32 accumulate; shfl_xor(8,16,32) combine; fp32 out.
// ---------------------------------------------------------------------------
__device__ __forceinline__ void addrow(float* acc, uint4 u)
{
    const __half2* h = reinterpret_cast<const __half2*>(&u);
    #pragma unroll
    for (int k = 0; k < 4; ++k) {
        float2 f = __half22float2(h[k]);
        acc[2 * k]     += f.x;
        acc[2 * k + 1] += f.y;
    }
}

__global__ __launch_bounds__(256) void gather_h(
    const __half* __restrict__ Yh,
    const int* __restrict__ offsets,
    const int* __restrict__ deg,
    const int* __restrict__ srt,
    const float* __restrict__ bias,
    float* __restrict__ out)
{
    const int wid  = threadIdx.x >> 6;
    const int lane = threadIdx.x & 63;
    const int g    = lane >> 3;          // edge slot within octet
    const int sub  = lane & 7;           // 16B chunk within 128B row
    const int node = blockIdx.x * 4 + wid;
    if (node >= N_NODES) return;

    const int start = offsets[node];
    const int cnt   = deg[node];

    float acc[8];
    #pragma unroll
    for (int j = 0; j < 8; ++j) acc[j] = 0.0f;

    if (g == 0) {        // self loop
        uint4 u = *reinterpret_cast<const uint4*>(Yh + (size_t)node * D + sub * 8);
        addrow(acc, u);
    }

    int e = 0;
    for (; e + 16 <= cnt; e += 16) {
        int s0 = srt[start + e + g];
        int s1 = srt[start + e + 8 + g];
        uint4 u0 = *reinterpret_cast<const uint4*>(Yh + (size_t)s0 * D + sub * 8);
        uint4 u1 = *reinterpret_cast<const uint4*>(Yh + (size_t)s1 * D + sub * 8);
        addrow(acc, u0);
        addrow(acc, u1);
    }
    if (e + 8 <= cnt) {
        int s0 = srt[start + e + g];
        uint4 u0 = *reinterpret_cast<const uint4*>(Yh + (size_t)s0 * D + sub * 8);
        addrow(acc, u0);
        e += 8;
    }
    if (e + g < cnt) {
        int s0 = srt[start + e + g];
        uint4 u0 = *reinterpret_cast<const uint4*>(Yh + (size_t)s0 * D + sub * 8);
        addrow(acc, u0);
    }

    // combine the 8 group partials (sub-aligned across groups)
    #pragma unroll
    for (int j = 0; j < 8; ++j) {
        acc[j] += __shfl_xor(acc[j], 8, 64);
        acc[j] += __shfl_xor(acc[j], 16, 64);
        acc[j] += __shfl_xor(acc[j], 32, 64);
    }

    if (g == 0) {
        const float sc = rsqrtf((float)cnt + 1.0f);
        const float4 b0 = *reinterpret_cast<const float4*>(bias + sub * 8);
        const float4 b1 = *reinterpret_cast<const float4*>(bias + sub * 8 + 4);
        float4 r0, r1;
        r0.x = acc[0] * sc + b0.x;  r0.y = acc[1] * sc + b0.y;
        r0.z = acc[2] * sc + b0.z;  r0.w = acc[3] * sc + b0.w;
        r1.x = acc[4] * sc + b1.x;  r1.y = acc[5] * sc + b1.y;
        r1.z = acc[6] * sc + b1.z;  r1.w = acc[7] * sc + b1.w;
        *reinterpret_cast<float4*>(out + (size_t)node * D + sub * 8)     = r0;
        *reinterpret_cast<float4*>(out + (size_t)node * D + sub * 8 + 4) = r1;
    }
}

// ---------------------------------------------------------------------------
// mid tier: round-0 proven pipeline (fp32 throughout)
// ---------------------------------------------------------------------------

__global__ __launch_bounds__(256) void linear_kernel(
    const float* __restrict__ vertices,
    const float* __restrict__ weight,
    float* __restrict__ Y)
{
    __shared__ float rowbuf[4][64];
    const int wid  = threadIdx.x >> 6;
    const int lane = threadIdx.x & 63;
    float w[64];
    #pragma unroll
    for (int f = 0; f < 64; ++f) w[f] = weight[lane * 64 + f];
    const int nodesPerIter = gridDim.x * 4;
    for (int base = blockIdx.x * 4; base < N_NODES; base += nodesPerIter) {
        const int node = base + wid;
        float a = 0.0f;
        if (node < N_NODES) a = vertices[(size_t)node * D + lane];
        rowbuf[wid][lane] = a;
        __syncthreads();
        float acc = 0.0f;
        #pragma unroll
        for (int f = 0; f < 64; ++f)
            acc += rowbuf[wid][f] * w[f];
        if (node < N_NODES) Y[(size_t)node * D + lane] = acc;
        __syncthreads();
    }
}

__global__ __launch_bounds__(256) void gather_f32(
    const float* __restrict__ Y,
    const int* __restrict__ offsets,
    const int* __restrict__ deg,
    const int* __restrict__ sortedSrc,
    const float* __restrict__ bias,
    float* __restrict__ out)
{
    const int wid  = threadIdx.x >> 6;
    const int lane = threadIdx.x & 63;
    const int g    = lane >> 4;
    const int sub  = lane & 15;
    const int node = blockIdx.x * 4 + wid;
    if (node >= N_NODES) return;

    const int start = offsets[node];
    const int cnt   = deg[node];

    float4 acc;
    if (g == 0) {
        acc = *reinterpret_cast<const float4*>(Y + (size_t)node * D + (sub << 2));
    } else {
        acc.x = 0.0f; acc.y = 0.0f; acc.z = 0.0f; acc.w = 0.0f;
    }

    int e = 0;
    for (; e + 8 <= cnt; e += 8) {
        int s0 = sortedSrc[start + e + g];
        int s1 = sortedSrc[start + e + 4 + g];
        const float4 a0 = *reinterpret_cast<const float4*>(Y + (size_t)s0 * D + (sub << 2));
        const float4 a1 = *reinterpret_cast<const float4*>(Y + (size_t)s1 * D + (sub << 2));
        acc.x += a0.x; acc.y += a0.y; acc.z += a0.z; acc.w += a0.w;
        acc.x += a1.x; acc.y += a1.y; acc.z += a1.z; acc.w += a1.w;
    }
    if (e + 4 <= cnt) {
        int s0 = sortedSrc[start + e + g];
        const float4 a0 = *reinterpret_cast<const float4*>(Y + (size_t)s0 * D + (sub << 2));
        acc.x += a0.x; acc.y += a0.y; acc.z += a0.z; acc.w += a0.w;
        e += 4;
    }
    if (e + g < cnt) {
        int s0 = sortedSrc[start + e + g];
        const float4 a0 = *reinterpret_cast<const float4*>(Y + (size_t)s0 * D + (sub << 2));
        acc.x += a0.x; acc.y += a0.y; acc.z += a0.z; acc.w += a0.w;
    }

    acc.x += __shfl_xor(acc.x, 16, 64);
    acc.y += __shfl_xor(acc.y, 16, 64);
    acc.z += __shfl_xor(acc.z, 16, 64);
    acc.w += __shfl_xor(acc.w, 16, 64);
    acc.x += __shfl_xor(acc.x, 32, 64);
    acc.y += __shfl_xor(acc.y, 32, 64);
    acc.z += __shfl_xor(acc.z, 32, 64);
    acc.w += __shfl_xor(acc.w, 32, 64);

    if (lane < 16) {
        const float sc = rsqrtf((float)cnt + 1.0f);
        const float4 b4 = *reinterpret_cast<const float4*>(bias + (sub << 2));
        float4 r;
        r.x = acc.x * sc + b4.x;
        r.y = acc.y * sc + b4.y;
        r.z = acc.z * sc + b4.z;
        r.w = acc.w * sc + b4.w;
        *reinterpret_cast<float4*>(out + (size_t)node * D + (sub << 2)) = r;
    }
}

__global__ __launch_bounds__(256) void hist_kernel(const int* __restrict__ edges,
                                                   int* __restrict__ deg)
{
    int e = blockIdx.x * 256 + threadIdx.x;
    if (e < N_EDGES) atomicAdd(&deg[edges[e]], 1);
}

__global__ __launch_bounds__(256) void scan_part(const int* __restrict__ deg,
                                                 int* __restrict__ partial)
{
    int t = threadIdx.x;
    int base = blockIdx.x * SCAN_CHUNK + t * 4;
    int s = 0;
    #pragma unroll
    for (int k = 0; k < 4; ++k) { int i = base + k; if (i < N_NODES) s += deg[i]; }
    int lane = t & 63, wid = t >> 6;
    #pragma unroll
    for (int off = 32; off; off >>= 1) s += __shfl_down(s, off, 64);
    __shared__ int red[4];
    if (lane == 0) red[wid] = s;
    __syncthreads();
    if (t == 0) partial[blockIdx.x] = red[0] + red[1] + red[2] + red[3];
}

__device__ __forceinline__ int waveInclScan(int v, int lane) {
    #pragma unroll
    for (int off = 1; off < 64; off <<= 1) {
        int t = __shfl_up(v, off, 64);
        if (lane >= off) v += t;
    }
    return v;
}

__global__ void scan_small(int* partial) {
    int lane = threadIdx.x;
    int v0 = (lane < NCHUNK) ? partial[lane] : 0;
    int v1 = (64 + lane < NCHUNK) ? partial[64 + lane] : 0;
    int i0 = waveInclScan(v0, lane);
    int tot0 = __shfl(i0, 63, 64);
    int i1 = waveInclScan(v1, lane) + tot0;
    if (lane < NCHUNK) partial[lane] = i0 - v0;
    if (64 + lane < NCHUNK) partial[64 + lane] = i1 - v1;
}

__global__ __launch_bounds__(256) void scan_final(const int* __restrict__ deg,
                                                  const int* __restrict__ partial,
                                                  int* __restrict__ offsets,
                                                  int* __restrict__ cursor)
{
    int t = threadIdx.x;
    int base = blockIdx.x * SCAN_CHUNK + t * 4;
    int d[4]; int s = 0;
    #pragma unroll
    for (int k = 0; k < 4; ++k) { int i = base + k; d[k] = (i < N_NODES) ? deg[i] : 0; s += d[k]; }
    __shared__ int sd[256];
    sd[t] = s; __syncthreads();
    #pragma unroll
    for (int off = 1; off < 256; off <<= 1) {
        int v = (t >= off) ? sd[t - off] : 0;
        __syncthreads();
        sd[t] += v;
        __syncthreads();
    }
    int excl = sd[t] - s + partial[blockIdx.x];
    #pragma unroll
    for (int k = 0; k < 4; ++k) {
        int i = base + k;
        if (i < N_NODES) { offsets[i] = excl; cursor[i] = excl; excl += d[k]; }
    }
}

__global__ __launch_bounds__(256) void scatter_idx(const int* __restrict__ edges,
                                                   int* __restrict__ cursor,
                                                   int* __restrict__ sortedSrc)
{
    int e = blockIdx.x * 256 + threadIdx.x;
    if (e >= N_EDGES) return;
    int dst = edges[e];
    int src = edges[N_EDGES + e];
    int pos = atomicAdd(&cursor[dst], 1);
    sortedSrc[pos] = src;
}

// ---------------------------------------------------------------------------
// last-resort fallback (round-1, proven)
// ---------------------------------------------------------------------------

__global__ __launch_bounds__(256) void fb_scatter(
    const float* __restrict__ vertices, const int* __restrict__ edges,
    float* __restrict__ agg, float* __restrict__ degF)
{
    long long tid = (long long)blockIdx.x * 256 + threadIdx.x;
    int lane = threadIdx.x & 63;
    long long e = tid >> 6;
    if (e >= N_EDGES) return;
    int dst = edges[e];
    int src = edges[N_EDGES + e];
    atomicAdd(&agg[(size_t)dst * D + lane], vertices[(size_t)src * D + lane]);
    if (lane == 0) atomicAdd(&degF[dst], 1.0f);
}

__global__ __launch_bounds__(256) void fb_finish(
    const float* __restrict__ vertices, const float* __restrict__ weight,
    const float* __restrict__ bias, const float* __restrict__ degF,
    float* __restrict__ out)
{
    __shared__ float rowbuf[4][64];
    const int wid  = threadIdx.x >> 6;
    const int lane = threadIdx.x & 63;
    float w[64];
    #pragma unroll
    for (int f = 0; f < 64; ++f) w[f] = weight[lane * 64 + f];
    const float b = bias[lane];
    const int nodesPerIter = gridDim.x * 4;
    for (int base = blockIdx.x * 4; base < N_NODES; base += nodesPerIter) {
        const int node = base + wid;
        float a = 0.0f;
        if (node < N_NODES) {
            const float scale = rsqrtf(degF[node] + 1.0f);
            a = (out[(size_t)node * D + lane] + vertices[(size_t)node * D + lane]) * scale;
        }
        rowbuf[wid][lane] = a;
        __syncthreads();
        float acc = b;
        #pragma unroll
        for (int f = 0; f < 64; ++f) acc += rowbuf[wid][f] * w[f];
        if (node < N_NODES) out[(size_t)node * D + lane] = acc;
        __syncthreads();
    }
}

extern "C" void kernel_launch(void* const* d_in, const int* in_sizes, int n_in,
                              void* d_out, int out_size, void* d_ws, size_t ws_size,
                              hipStream_t stream) {
    const float* vertices = (const float*)d_in[0];
    const int*   edges    = (const int*)d_in[1];
    const float* weight   = (const float*)d_in[2];
    const float* bias     = (const float*)d_in[3];
    float* out = (float*)d_out;

    const int threads = 256;
    const int edgeBlocks = (N_EDGES + threads - 1) / threads;

    // --- fast layout: Yh(fp16) | H[SPLITB*NB] | colsum | bbase | offs | deg | packed | srt
    {
        __half* Yh    = (__half*)d_ws;
        int*   H      = (int*)(Yh + (size_t)N_NODES * D);
        int*   colsum = H + SPLITB * NB;
        int*   bbase  = colsum + NB;
        int*   offs   = bbase + NB;
        int*   deg    = offs + N_NODES;
        int*   packed = deg + N_NODES;
        int*   srt    = packed + N_EDGES;
        size_t needed = (size_t)((char*)(srt + N_EDGES) - (char*)d_ws);
        if (ws_size >= needed) {
            lin_hist<<<LINB + SPLITB, threads, 0, stream>>>(vertices, weight, Yh, edges, H);
            s_scanA<<<NB, threads, 0, stream>>>(H, colsum);
            s_scanB<<<1, threads, 0, stream>>>(colsum, bbase);
            s_scatter<<<SPLITB, threads, 0, stream>>>(edges, H, bbase, packed);
            bucket_csr<<<NB, threads, 0, stream>>>(packed, bbase, colsum, offs, deg, srt);
            gather_h<<<(N_NODES + 3) / 4, threads, 0, stream>>>(Yh, offs, deg, srt, bias, out);
            return;
        }
    }

    // --- mid layout (round-0 proven): Y | deg | offsets | cursor | partial[128] | srt
    {
        float* Y       = (float*)d_ws;
        int*   deg     = (int*)(Y + (size_t)N_NODES * D);
        int*   offs    = deg + N_NODES;
        int*   cursor  = offs + N_NODES;
        int*   partial = cursor + N_NODES;
        int*   srt     = partial + 128;
        size_t needed  = (size_t)((char*)(srt + N_EDGES) - (char*)d_ws);
        if (ws_size >= needed) {
            hipMemsetAsync(deg, 0, sizeof(int) * N_NODES, stream);
            linear_kernel<<<1024, threads, 0, stream>>>(vertices, weight, Y);
            hist_kernel<<<edgeBlocks, threads, 0, stream>>>(edges, deg);
            scan_part<<<NCHUNK, threads, 0, stream>>>(deg, partial);
            scan_small<<<1, 64, 0, stream>>>(partial);
            scan_final<<<NCHUNK, threads, 0, stream>>>(deg, partial, offs, cursor);
            scatter_idx<<<edgeBlocks, threads, 0, stream>>>(edges, cursor, srt);
            gather_f32<<<(N_NODES + 3) / 4, threads, 0, stream>>>(Y, offs, deg, srt, bias, out);
            return;
        }
    }

    // --- last resort
    {
        float* degF = (float*)d_ws;
        hipMemsetAsync(out, 0, sizeof(float) * (size_t)N_NODES * D, stream);
        hipMemsetAsync(degF, 0, sizeof(float) * N_NODES, stream);
        const long long totalScatter = (long long)N_EDGES * 64;
        fb_scatter<<<(int)((totalScatter + threads - 1) / threads), threads, 0, stream>>>(
            vertices, edges, out, degF);
        fb_finish<<<1024, threads, 0, stream>>>(vertices, weight, bias, degF, out);
    }
}